// Round 2
// baseline (1298.709 us; speedup 1.0000x reference)
//
#include <hip/hip_runtime.h>
#include <hip/hip_bf16.h>
#include <stdint.h>

#define NN 100000
#define NFEATD 256
#define NHIDD 512
#define NCLASSD 256

typedef short bf16x8 __attribute__((ext_vector_type(8)));
typedef float f32x4 __attribute__((ext_vector_type(4)));

__device__ __forceinline__ float bf2f(uint32_t u) {
    union { uint32_t i; float f; } v; v.i = u << 16; return v.f;
}
__device__ __forceinline__ ushort f2bf(float f) {
    uint32_t x = __float_as_uint(f);
    uint32_t r = (x + 0x7FFF + ((x >> 16) & 1)) >> 16;
    return (ushort)r;
}

// ---------------- small utility kernels ----------------
__global__ void zero_i32(int* __restrict__ p, int n) {
    int i = blockIdx.x * 256 + threadIdx.x;
    if (i < n) p[i] = 0;
}

__global__ void count_deg(const int* __restrict__ dst, int* __restrict__ deg, int nE) {
    int e = blockIdx.x * 256 + threadIdx.x;
    if (e < nE) atomicAdd(&deg[dst[e]], 1);
}

// single-block exclusive scan over n ints (n up to ~few hundred K), 1024 threads
__global__ __launch_bounds__(1024) void scan_excl(const int* __restrict__ deg,
                                                  int* __restrict__ off, int n) {
    __shared__ int wsum[16];
    __shared__ int carry_s;
    const int tid = threadIdx.x;
    const int lane = tid & 63, wv = tid >> 6;
    if (tid == 0) carry_s = 0;
    __syncthreads();
    for (int base = 0; base < n; base += 1024) {
        int i = base + tid;
        int v = (i < n) ? deg[i] : 0;
        int x = v;
#pragma unroll
        for (int d = 1; d < 64; d <<= 1) {
            int y = __shfl_up(x, d, 64);
            if (lane >= d) x += y;
        }
        if (lane == 63) wsum[wv] = x;
        __syncthreads();
        if (wv == 0 && lane < 16) {
            int s = wsum[lane];
#pragma unroll
            for (int d = 1; d < 16; d <<= 1) {
                int y = __shfl_up(s, d, 16);
                if (lane >= d) s += y;
            }
            wsum[lane] = s;
        }
        __syncthreads();
        int carry = carry_s;
        int wprefix = (wv == 0) ? 0 : wsum[wv - 1];
        if (i < n) off[i] = carry + wprefix + x - v;
        __syncthreads();
        if (tid == 0) carry_s = carry + wsum[15];
        __syncthreads();
    }
    if (tid == 0) off[n] = carry_s;
}

__global__ void fill_csr(const int* __restrict__ src, const int* __restrict__ dst,
                         const int* __restrict__ off, int* __restrict__ cursor,
                         int* __restrict__ csr, int nE) {
    int e = blockIdx.x * 256 + threadIdx.x;
    if (e >= nE) return;
    int d = dst[e];
    int p = off[d] + atomicAdd(&cursor[d], 1);
    csr[p] = src[e];
}

// ---------------- weight prep: [K][N] f32 -> [N][K] bf16 ----------------
__global__ void prep_w(const float* __restrict__ W, ushort* __restrict__ Wt, int K, int N) {
    int idx = blockIdx.x * 256 + threadIdx.x;
    if (idx >= K * N) return;
    int k = idx / N, n = idx - k * N;
    Wt[(size_t)n * K + k] = f2bf(W[idx]);
}

// ---------------- CSR gather: agg[n] = (1+eps)*x[n] + sum_{s in nbr(n)} x[s] ---------
// one wave per node, F=256 f32 input -> bf16 out
__global__ void gather256(const float* __restrict__ X, const int* __restrict__ off,
                          const int* __restrict__ csr, const float* __restrict__ eps,
                          ushort* __restrict__ out) {
    int node = (blockIdx.x * 256 + threadIdx.x) >> 6;
    if (node >= NN) return;
    int lane = threadIdx.x & 63;
    const float4* X4 = (const float4*)X;  // 64 float4 per row
    float sc = 1.0f + *eps;
    float4 a = X4[(size_t)node * 64 + lane];
    float ax = a.x * sc, ay = a.y * sc, az = a.z * sc, aw = a.w * sc;
    int e = off[node], e1 = off[node + 1];
    for (; e + 1 < e1; e += 2) {
        int s0 = csr[e], s1 = csr[e + 1];
        float4 v0 = X4[(size_t)s0 * 64 + lane];
        float4 v1 = X4[(size_t)s1 * 64 + lane];
        ax += v0.x + v1.x; ay += v0.y + v1.y;
        az += v0.z + v1.z; aw += v0.w + v1.w;
    }
    if (e < e1) {
        int s0 = csr[e];
        float4 v0 = X4[(size_t)s0 * 64 + lane];
        ax += v0.x; ay += v0.y; az += v0.z; aw += v0.w;
    }
    uint2 r;
    r.x = (uint32_t)f2bf(ax) | ((uint32_t)f2bf(ay) << 16);
    r.y = (uint32_t)f2bf(az) | ((uint32_t)f2bf(aw) << 16);
    *(uint2*)(out + (size_t)node * 256 + lane * 4) = r;
}

// one wave per node, F=512 bf16 input -> bf16 out
__global__ void gather512(const ushort* __restrict__ H, const int* __restrict__ off,
                          const int* __restrict__ csr, const float* __restrict__ eps,
                          ushort* __restrict__ out) {
    int node = (blockIdx.x * 256 + threadIdx.x) >> 6;
    if (node >= NN) return;
    int lane = threadIdx.x & 63;
    float sc = 1.0f + *eps;
    float acc[8];
    {
        uint4 p = *(const uint4*)(H + (size_t)node * 512 + lane * 8);
        acc[0] = sc * bf2f(p.x & 0xffff); acc[1] = sc * bf2f(p.x >> 16);
        acc[2] = sc * bf2f(p.y & 0xffff); acc[3] = sc * bf2f(p.y >> 16);
        acc[4] = sc * bf2f(p.z & 0xffff); acc[5] = sc * bf2f(p.z >> 16);
        acc[6] = sc * bf2f(p.w & 0xffff); acc[7] = sc * bf2f(p.w >> 16);
    }
    int e = off[node], e1 = off[node + 1];
    for (; e + 1 < e1; e += 2) {
        int s0 = csr[e], s1 = csr[e + 1];
        uint4 p0 = *(const uint4*)(H + (size_t)s0 * 512 + lane * 8);
        uint4 p1 = *(const uint4*)(H + (size_t)s1 * 512 + lane * 8);
        acc[0] += bf2f(p0.x & 0xffff) + bf2f(p1.x & 0xffff);
        acc[1] += bf2f(p0.x >> 16)    + bf2f(p1.x >> 16);
        acc[2] += bf2f(p0.y & 0xffff) + bf2f(p1.y & 0xffff);
        acc[3] += bf2f(p0.y >> 16)    + bf2f(p1.y >> 16);
        acc[4] += bf2f(p0.z & 0xffff) + bf2f(p1.z & 0xffff);
        acc[5] += bf2f(p0.z >> 16)    + bf2f(p1.z >> 16);
        acc[6] += bf2f(p0.w & 0xffff) + bf2f(p1.w & 0xffff);
        acc[7] += bf2f(p0.w >> 16)    + bf2f(p1.w >> 16);
    }
    if (e < e1) {
        int s0 = csr[e];
        uint4 p0 = *(const uint4*)(H + (size_t)s0 * 512 + lane * 8);
        acc[0] += bf2f(p0.x & 0xffff); acc[1] += bf2f(p0.x >> 16);
        acc[2] += bf2f(p0.y & 0xffff); acc[3] += bf2f(p0.y >> 16);
        acc[4] += bf2f(p0.z & 0xffff); acc[5] += bf2f(p0.z >> 16);
        acc[6] += bf2f(p0.w & 0xffff); acc[7] += bf2f(p0.w >> 16);
    }
    uint4 r;
    r.x = (uint32_t)f2bf(acc[0]) | ((uint32_t)f2bf(acc[1]) << 16);
    r.y = (uint32_t)f2bf(acc[2]) | ((uint32_t)f2bf(acc[3]) << 16);
    r.z = (uint32_t)f2bf(acc[4]) | ((uint32_t)f2bf(acc[5]) << 16);
    r.w = (uint32_t)f2bf(acc[6]) | ((uint32_t)f2bf(acc[7]) << 16);
    *(uint4*)(out + (size_t)node * 512 + lane * 8) = r;
}

// ---------------- GEMM: C[M,N] = A[M,K](bf16) * Bt[N,K](bf16)^T + bias, opt relu ----
// m97-style: 128x128 tile, BK=32, 4 waves (2x2), each wave 4x4 frags of 16x16x32
__global__ __launch_bounds__(256) void gemm_bt(
    const ushort* __restrict__ A, const ushort* __restrict__ Bt,
    const float* __restrict__ bias, float* __restrict__ outf,
    ushort* __restrict__ outb, int M, int N, int K, int relu)
{
    __shared__ ushort As[128 * 32];
    __shared__ ushort Bs[128 * 32];
    const int tid = threadIdx.x;
    const int wave = tid >> 6, lane = tid & 63;
    const int quad = lane >> 4, lrow = lane & 15;
    const int wr = wave >> 1, wc = wave & 1;
    const int row0 = blockIdx.x * 128, col0 = blockIdx.y * 128;

    f32x4 acc[4][4] = {};

    for (int k0 = 0; k0 < K; k0 += 32) {
#pragma unroll
        for (int it = 0; it < 2; ++it) {
            int chunk = it * 256 + tid;        // lds dst = wave-uniform base + lane*16B
            int r = chunk >> 2, c = chunk & 3;
            int gr = row0 + r; if (gr > M - 1) gr = M - 1;
            const ushort* gp = A + (size_t)gr * K + (k0 + c * 8);
            __builtin_amdgcn_global_load_lds((const __attribute__((address_space(1))) void*)gp,
                (__attribute__((address_space(3))) void*)(As + chunk * 8), 16, 0, 0);
        }
#pragma unroll
        for (int it = 0; it < 2; ++it) {
            int chunk = it * 256 + tid;
            int r = chunk >> 2, c = chunk & 3;
            const ushort* gp = Bt + (size_t)(col0 + r) * K + (k0 + c * 8);
            __builtin_amdgcn_global_load_lds((const __attribute__((address_space(1))) void*)gp,
                (__attribute__((address_space(3))) void*)(Bs + chunk * 8), 16, 0, 0);
        }
        __syncthreads();

        bf16x8 af[4], bfr[4];
#pragma unroll
        for (int i = 0; i < 4; ++i)
            af[i] = *(const bf16x8*)(As + (wr * 64 + i * 16 + lrow) * 32 + quad * 8);
#pragma unroll
        for (int j = 0; j < 4; ++j)
            bfr[j] = *(const bf16x8*)(Bs + (wc * 64 + j * 16 + lrow) * 32 + quad * 8);
#pragma unroll
        for (int i = 0; i < 4; ++i)
#pragma unroll
            for (int j = 0; j < 4; ++j)
                acc[i][j] = __builtin_amdgcn_mfma_f32_16x16x32_bf16(af[i], bfr[j], acc[i][j], 0, 0, 0);
        __syncthreads();
    }

    // epilogue: C/D layout col=lane&15, row=quad*4+reg
#pragma unroll
    for (int i = 0; i < 4; ++i) {
        int rbase = row0 + wr * 64 + i * 16 + quad * 4;
#pragma unroll
        for (int j = 0; j < 4; ++j) {
            int c = col0 + wc * 64 + j * 16 + lrow;
            float bv = bias[c];
#pragma unroll
            for (int g = 0; g < 4; ++g) {
                int rr = rbase + g;
                if (rr < M) {
                    float v = acc[i][j][g] + bv;
                    if (relu) v = fmaxf(v, 0.f);
                    if (outf) outf[(size_t)rr * N + c] = v;
                    else      outb[(size_t)rr * N + c] = f2bf(v);
                }
            }
        }
    }
}

extern "C" void kernel_launch(void* const* d_in, const int* in_sizes, int n_in,
                              void* d_out, int out_size, void* d_ws, size_t ws_size,
                              hipStream_t stream) {
    const float* x    = (const float*)d_in[0];
    const int*   ei   = (const int*)d_in[1];
    const float* W1a  = (const float*)d_in[2];
    const float* b1a  = (const float*)d_in[3];
    const float* W1b  = (const float*)d_in[4];
    const float* b1b  = (const float*)d_in[5];
    const float* W2a  = (const float*)d_in[6];
    const float* b2a  = (const float*)d_in[7];
    const float* W2b  = (const float*)d_in[8];
    const float* b2b  = (const float*)d_in[9];
    const float* eps1 = (const float*)d_in[10];
    const float* eps2 = (const float*)d_in[11];
    const int nE = in_sizes[1] / 2;
    const int* srcv = ei;
    const int* dstv = ei + nE;

    // ---- compact workspace layout (total ~215.3 MB) ----
    char* ws = (char*)d_ws;
    int*    off    = (int*)(ws);                        // 100001 ints  [0, 512K)
    int*    cursor = (int*)(ws + 524288);               // 100000 ints  [512K, 1M)
    int*    csr    = (int*)(ws + 1048576);              // 1.6M ints    [1M, ~7.4M)
    ushort* Wt1a   = (ushort*)(ws + 8388608);           // [512][256] bf16
    ushort* Wt1b   = Wt1a + 512 * 256;                  // [512][512]
    ushort* Wt2a   = Wt1b + 512 * 512;                  // [512][512]
    ushort* Wt2b   = Wt2a + 512 * 512;                  // [256][512]
    char*   P      = ws + 10485760;                     // 102,400,000 B slot
    char*   Q      = ws + 10485760 + 102400000;         // 102,400,000 B slot
    ushort* agg1b  = (ushort*)Q;   // [100000,256] bf16 (dead before h2 written)
    ushort* h1     = (ushort*)P;   // [100000,512]
    ushort* h2     = (ushort*)Q;   // [100000,512]
    ushort* agg2b  = (ushort*)P;   // [100000,512] (h1 dead)
    ushort* h3     = (ushort*)Q;   // [100000,512] (h2 dead)

    // ---- CSR build (by dst) ----
    zero_i32<<<(NN + 255) / 256, 256, 0, stream>>>(cursor, NN);
    count_deg<<<(nE + 255) / 256, 256, 0, stream>>>(dstv, cursor, nE);
    scan_excl<<<1, 1024, 0, stream>>>(cursor, off, NN);
    zero_i32<<<(NN + 255) / 256, 256, 0, stream>>>(cursor, NN);
    fill_csr<<<(nE + 255) / 256, 256, 0, stream>>>(srcv, dstv, off, cursor, csr, nE);

    // ---- weights -> bf16 transposed ----
    prep_w<<<(NFEATD * NHIDD + 255) / 256, 256, 0, stream>>>(W1a, Wt1a, NFEATD, NHIDD);
    prep_w<<<(NHIDD * NHIDD + 255) / 256, 256, 0, stream>>>(W1b, Wt1b, NHIDD, NHIDD);
    prep_w<<<(NHIDD * NHIDD + 255) / 256, 256, 0, stream>>>(W2a, Wt2a, NHIDD, NHIDD);
    prep_w<<<(NHIDD * NCLASSD + 255) / 256, 256, 0, stream>>>(W2b, Wt2b, NHIDD, NCLASSD);

    // ---- layer 1: agg -> MLP ----
    gather256<<<(NN * 64) / 256, 256, 0, stream>>>(x, off, csr, eps1, agg1b);
    dim3 g1((NN + 127) / 128, NHIDD / 128);
    gemm_bt<<<g1, 256, 0, stream>>>(agg1b, Wt1a, b1a, nullptr, h1, NN, NHIDD, NFEATD, 1);
    gemm_bt<<<g1, 256, 0, stream>>>(h1, Wt1b, b1b, nullptr, h2, NN, NHIDD, NHIDD, 1);

    // ---- layer 2: agg -> MLP ----
    gather512<<<(NN * 64) / 256, 256, 0, stream>>>(h2, off, csr, eps2, agg2b);
    gemm_bt<<<g1, 256, 0, stream>>>(agg2b, Wt2a, b2a, nullptr, h3, NN, NHIDD, NHIDD, 1);
    dim3 g2((NN + 127) / 128, NCLASSD / 128);
    gemm_bt<<<g2, 256, 0, stream>>>(h3, Wt2b, b2b, (float*)d_out, nullptr, NN, NCLASSD, NHIDD, 0);
}

// Round 3
// 1178.059 us; speedup vs baseline: 1.1024x; 1.1024x over previous
//
#include <hip/hip_runtime.h>
#include <hip/hip_bf16.h>
#include <stdint.h>

#define NN 100000
#define NFEATD 256
#define NHIDD 512
#define NCLASSD 256

typedef short bf16x8 __attribute__((ext_vector_type(8)));
typedef float f32x4 __attribute__((ext_vector_type(4)));

__device__ __forceinline__ float bf2f(uint32_t u) {
    union { uint32_t i; float f; } v; v.i = u << 16; return v.f;
}
__device__ __forceinline__ ushort f2bf(float f) {
    uint32_t x = __float_as_uint(f);
    uint32_t r = (x + 0x7FFF + ((x >> 16) & 1)) >> 16;
    return (ushort)r;
}

// ---------------- small utility kernels ----------------
__global__ void zero_i32(int* __restrict__ p, int n) {
    int i = blockIdx.x * 256 + threadIdx.x;
    if (i < n) p[i] = 0;
}

__global__ void count_deg(const int* __restrict__ dst, int* __restrict__ deg, int nE) {
    int e = blockIdx.x * 256 + threadIdx.x;
    if (e < nE) atomicAdd(&deg[dst[e]], 1);
}

// single-block exclusive scan over n ints, 1024 threads
__global__ __launch_bounds__(1024) void scan_excl(const int* __restrict__ deg,
                                                  int* __restrict__ off, int n) {
    __shared__ int wsum[16];
    __shared__ int carry_s;
    const int tid = threadIdx.x;
    const int lane = tid & 63, wv = tid >> 6;
    if (tid == 0) carry_s = 0;
    __syncthreads();
    for (int base = 0; base < n; base += 1024) {
        int i = base + tid;
        int v = (i < n) ? deg[i] : 0;
        int x = v;
#pragma unroll
        for (int d = 1; d < 64; d <<= 1) {
            int y = __shfl_up(x, d, 64);
            if (lane >= d) x += y;
        }
        if (lane == 63) wsum[wv] = x;
        __syncthreads();
        if (wv == 0 && lane < 16) {
            int s = wsum[lane];
#pragma unroll
            for (int d = 1; d < 16; d <<= 1) {
                int y = __shfl_up(s, d, 16);
                if (lane >= d) s += y;
            }
            wsum[lane] = s;
        }
        __syncthreads();
        int carry = carry_s;
        int wprefix = (wv == 0) ? 0 : wsum[wv - 1];
        if (i < n) off[i] = carry + wprefix + x - v;
        __syncthreads();
        if (tid == 0) carry_s = carry + wsum[15];
        __syncthreads();
    }
    if (tid == 0) off[n] = carry_s;
}

__global__ void fill_csr(const int* __restrict__ src, const int* __restrict__ dst,
                         const int* __restrict__ off, int* __restrict__ cursor,
                         int* __restrict__ csr, int nE) {
    int e = blockIdx.x * 256 + threadIdx.x;
    if (e >= nE) return;
    int d = dst[e];
    int p = off[d] + atomicAdd(&cursor[d], 1);
    csr[p] = src[e];
}

// ---------------- weight prep: [K][N] f32 -> [N][K] bf16 ----------------
__global__ void prep_w(const float* __restrict__ W, ushort* __restrict__ Wt, int K, int N) {
    int idx = blockIdx.x * 256 + threadIdx.x;
    if (idx >= K * N) return;
    int k = idx / N, n = idx - k * N;
    Wt[(size_t)n * K + k] = f2bf(W[idx]);
}

// f32 -> bf16 cast, 8 elems/thread
__global__ void cast_f32_bf16(const float* __restrict__ a, ushort* __restrict__ o, int n) {
    int i = (blockIdx.x * 256 + threadIdx.x) * 8;
    if (i >= n) return;
    float4 v0 = *(const float4*)(a + i);
    float4 v1 = *(const float4*)(a + i + 4);
    uint4 r;
    r.x = (uint32_t)f2bf(v0.x) | ((uint32_t)f2bf(v0.y) << 16);
    r.y = (uint32_t)f2bf(v0.z) | ((uint32_t)f2bf(v0.w) << 16);
    r.z = (uint32_t)f2bf(v1.x) | ((uint32_t)f2bf(v1.y) << 16);
    r.w = (uint32_t)f2bf(v1.z) | ((uint32_t)f2bf(v1.w) << 16);
    *(uint4*)(o + i) = r;
}

// ---------------- CSR gather: agg[n] = (1+eps)*x[n] + sum_{s in nbr(n)} x[s] ---------
// one wave per node, F=256 bf16 input (uint2/lane = 4 bf16), unroll 4
__global__ void gather256b(const ushort* __restrict__ X, const int* __restrict__ off,
                           const int* __restrict__ csr, const float* __restrict__ eps,
                           ushort* __restrict__ out) {
    int node = (blockIdx.x * 256 + threadIdx.x) >> 6;
    if (node >= NN) return;
    int lane = threadIdx.x & 63;
    float sc = 1.0f + *eps;
    float a0, a1, a2, a3;
    {
        uint2 p = *(const uint2*)(X + (size_t)node * 256 + lane * 4);
        a0 = sc * bf2f(p.x & 0xffff); a1 = sc * bf2f(p.x >> 16);
        a2 = sc * bf2f(p.y & 0xffff); a3 = sc * bf2f(p.y >> 16);
    }
    int e = off[node], e1 = off[node + 1];
    for (; e + 3 < e1; e += 4) {
        int s0 = csr[e], s1 = csr[e + 1], s2 = csr[e + 2], s3 = csr[e + 3];
        uint2 p0 = *(const uint2*)(X + (size_t)s0 * 256 + lane * 4);
        uint2 p1 = *(const uint2*)(X + (size_t)s1 * 256 + lane * 4);
        uint2 p2 = *(const uint2*)(X + (size_t)s2 * 256 + lane * 4);
        uint2 p3 = *(const uint2*)(X + (size_t)s3 * 256 + lane * 4);
        a0 += bf2f(p0.x & 0xffff) + bf2f(p1.x & 0xffff) + bf2f(p2.x & 0xffff) + bf2f(p3.x & 0xffff);
        a1 += bf2f(p0.x >> 16)    + bf2f(p1.x >> 16)    + bf2f(p2.x >> 16)    + bf2f(p3.x >> 16);
        a2 += bf2f(p0.y & 0xffff) + bf2f(p1.y & 0xffff) + bf2f(p2.y & 0xffff) + bf2f(p3.y & 0xffff);
        a3 += bf2f(p0.y >> 16)    + bf2f(p1.y >> 16)    + bf2f(p2.y >> 16)    + bf2f(p3.y >> 16);
    }
    for (; e < e1; ++e) {
        int s0 = csr[e];
        uint2 p0 = *(const uint2*)(X + (size_t)s0 * 256 + lane * 4);
        a0 += bf2f(p0.x & 0xffff); a1 += bf2f(p0.x >> 16);
        a2 += bf2f(p0.y & 0xffff); a3 += bf2f(p0.y >> 16);
    }
    uint2 r;
    r.x = (uint32_t)f2bf(a0) | ((uint32_t)f2bf(a1) << 16);
    r.y = (uint32_t)f2bf(a2) | ((uint32_t)f2bf(a3) << 16);
    *(uint2*)(out + (size_t)node * 256 + lane * 4) = r;
}

// one wave per node, F=512 bf16 input (uint4/lane = 8 bf16), unroll 4
__global__ void gather512(const ushort* __restrict__ H, const int* __restrict__ off,
                          const int* __restrict__ csr, const float* __restrict__ eps,
                          ushort* __restrict__ out) {
    int node = (blockIdx.x * 256 + threadIdx.x) >> 6;
    if (node >= NN) return;
    int lane = threadIdx.x & 63;
    float sc = 1.0f + *eps;
    float acc[8];
    {
        uint4 p = *(const uint4*)(H + (size_t)node * 512 + lane * 8);
        acc[0] = sc * bf2f(p.x & 0xffff); acc[1] = sc * bf2f(p.x >> 16);
        acc[2] = sc * bf2f(p.y & 0xffff); acc[3] = sc * bf2f(p.y >> 16);
        acc[4] = sc * bf2f(p.z & 0xffff); acc[5] = sc * bf2f(p.z >> 16);
        acc[6] = sc * bf2f(p.w & 0xffff); acc[7] = sc * bf2f(p.w >> 16);
    }
    int e = off[node], e1 = off[node + 1];
    for (; e + 3 < e1; e += 4) {
        int s0 = csr[e], s1 = csr[e + 1], s2 = csr[e + 2], s3 = csr[e + 3];
        uint4 p0 = *(const uint4*)(H + (size_t)s0 * 512 + lane * 8);
        uint4 p1 = *(const uint4*)(H + (size_t)s1 * 512 + lane * 8);
        uint4 p2 = *(const uint4*)(H + (size_t)s2 * 512 + lane * 8);
        uint4 p3 = *(const uint4*)(H + (size_t)s3 * 512 + lane * 8);
        acc[0] += bf2f(p0.x & 0xffff) + bf2f(p1.x & 0xffff) + bf2f(p2.x & 0xffff) + bf2f(p3.x & 0xffff);
        acc[1] += bf2f(p0.x >> 16)    + bf2f(p1.x >> 16)    + bf2f(p2.x >> 16)    + bf2f(p3.x >> 16);
        acc[2] += bf2f(p0.y & 0xffff) + bf2f(p1.y & 0xffff) + bf2f(p2.y & 0xffff) + bf2f(p3.y & 0xffff);
        acc[3] += bf2f(p0.y >> 16)    + bf2f(p1.y >> 16)    + bf2f(p2.y >> 16)    + bf2f(p3.y >> 16);
        acc[4] += bf2f(p0.z & 0xffff) + bf2f(p1.z & 0xffff) + bf2f(p2.z & 0xffff) + bf2f(p3.z & 0xffff);
        acc[5] += bf2f(p0.z >> 16)    + bf2f(p1.z >> 16)    + bf2f(p2.z >> 16)    + bf2f(p3.z >> 16);
        acc[6] += bf2f(p0.w & 0xffff) + bf2f(p1.w & 0xffff) + bf2f(p2.w & 0xffff) + bf2f(p3.w & 0xffff);
        acc[7] += bf2f(p0.w >> 16)    + bf2f(p1.w >> 16)    + bf2f(p2.w >> 16)    + bf2f(p3.w >> 16);
    }
    for (; e < e1; ++e) {
        int s0 = csr[e];
        uint4 p0 = *(const uint4*)(H + (size_t)s0 * 512 + lane * 8);
        acc[0] += bf2f(p0.x & 0xffff); acc[1] += bf2f(p0.x >> 16);
        acc[2] += bf2f(p0.y & 0xffff); acc[3] += bf2f(p0.y >> 16);
        acc[4] += bf2f(p0.z & 0xffff); acc[5] += bf2f(p0.z >> 16);
        acc[6] += bf2f(p0.w & 0xffff); acc[7] += bf2f(p0.w >> 16);
    }
    uint4 r;
    r.x = (uint32_t)f2bf(acc[0]) | ((uint32_t)f2bf(acc[1]) << 16);
    r.y = (uint32_t)f2bf(acc[2]) | ((uint32_t)f2bf(acc[3]) << 16);
    r.z = (uint32_t)f2bf(acc[4]) | ((uint32_t)f2bf(acc[5]) << 16);
    r.w = (uint32_t)f2bf(acc[6]) | ((uint32_t)f2bf(acc[7]) << 16);
    *(uint4*)(out + (size_t)node * 512 + lane * 8) = r;
}

// ---------------- GEMM: C[M,N] = A[M,K](bf16) * Bt[N,K](bf16)^T + bias, opt relu ----
// m97-style: 128x128 tile, BK=32, 4 waves (2x2), each wave 4x4 frags of 16x16x32
__global__ __launch_bounds__(256) void gemm_bt(
    const ushort* __restrict__ A, const ushort* __restrict__ Bt,
    const float* __restrict__ bias, float* __restrict__ outf,
    ushort* __restrict__ outb, int M, int N, int K, int relu)
{
    __shared__ ushort As[128 * 32];
    __shared__ ushort Bs[128 * 32];
    const int tid = threadIdx.x;
    const int wave = tid >> 6, lane = tid & 63;
    const int quad = lane >> 4, lrow = lane & 15;
    const int wr = wave >> 1, wc = wave & 1;
    const int row0 = blockIdx.x * 128, col0 = blockIdx.y * 128;

    f32x4 acc[4][4] = {};

    for (int k0 = 0; k0 < K; k0 += 32) {
#pragma unroll
        for (int it = 0; it < 2; ++it) {
            int chunk = it * 256 + tid;        // lds dst = wave-uniform base + lane*16B
            int r = chunk >> 2, c = chunk & 3;
            int gr = row0 + r; if (gr > M - 1) gr = M - 1;
            const ushort* gp = A + (size_t)gr * K + (k0 + c * 8);
            __builtin_amdgcn_global_load_lds((const __attribute__((address_space(1))) void*)gp,
                (__attribute__((address_space(3))) void*)(As + chunk * 8), 16, 0, 0);
        }
#pragma unroll
        for (int it = 0; it < 2; ++it) {
            int chunk = it * 256 + tid;
            int r = chunk >> 2, c = chunk & 3;
            const ushort* gp = Bt + (size_t)(col0 + r) * K + (k0 + c * 8);
            __builtin_amdgcn_global_load_lds((const __attribute__((address_space(1))) void*)gp,
                (__attribute__((address_space(3))) void*)(Bs + chunk * 8), 16, 0, 0);
        }
        __syncthreads();

        bf16x8 af[4], bfr[4];
#pragma unroll
        for (int i = 0; i < 4; ++i)
            af[i] = *(const bf16x8*)(As + (wr * 64 + i * 16 + lrow) * 32 + quad * 8);
#pragma unroll
        for (int j = 0; j < 4; ++j)
            bfr[j] = *(const bf16x8*)(Bs + (wc * 64 + j * 16 + lrow) * 32 + quad * 8);
#pragma unroll
        for (int i = 0; i < 4; ++i)
#pragma unroll
            for (int j = 0; j < 4; ++j)
                acc[i][j] = __builtin_amdgcn_mfma_f32_16x16x32_bf16(af[i], bfr[j], acc[i][j], 0, 0, 0);
        __syncthreads();
    }

    // epilogue: C/D layout col=lane&15, row=quad*4+reg
#pragma unroll
    for (int i = 0; i < 4; ++i) {
        int rbase = row0 + wr * 64 + i * 16 + quad * 4;
#pragma unroll
        for (int j = 0; j < 4; ++j) {
            int c = col0 + wc * 64 + j * 16 + lrow;
            float bv = bias[c];
#pragma unroll
            for (int g = 0; g < 4; ++g) {
                int rr = rbase + g;
                if (rr < M) {
                    float v = acc[i][j][g] + bv;
                    if (relu) v = fmaxf(v, 0.f);
                    if (outf) outf[(size_t)rr * N + c] = v;
                    else      outb[(size_t)rr * N + c] = f2bf(v);
                }
            }
        }
    }
}

extern "C" void kernel_launch(void* const* d_in, const int* in_sizes, int n_in,
                              void* d_out, int out_size, void* d_ws, size_t ws_size,
                              hipStream_t stream) {
    const float* x    = (const float*)d_in[0];
    const int*   ei   = (const int*)d_in[1];
    const float* W1a  = (const float*)d_in[2];
    const float* b1a  = (const float*)d_in[3];
    const float* W1b  = (const float*)d_in[4];
    const float* b1b  = (const float*)d_in[5];
    const float* W2a  = (const float*)d_in[6];
    const float* b2a  = (const float*)d_in[7];
    const float* W2b  = (const float*)d_in[8];
    const float* b2b  = (const float*)d_in[9];
    const float* eps1 = (const float*)d_in[10];
    const float* eps2 = (const float*)d_in[11];
    const int nE = in_sizes[1] / 2;
    const int* srcv = ei;
    const int* dstv = ei + nE;

    // ---- compact workspace layout (total ~215.3 MB) ----
    char* ws = (char*)d_ws;
    int*    off    = (int*)(ws);                        // 100001 ints
    int*    cursor = (int*)(ws + 524288);               // 100000 ints
    int*    csr    = (int*)(ws + 1048576);              // 1.6M ints
    ushort* Wt1a   = (ushort*)(ws + 8388608);           // [512][256] bf16
    ushort* Wt1b   = Wt1a + 512 * 256;                  // [512][512]
    ushort* Wt2a   = Wt1b + 512 * 512;                  // [512][512]
    ushort* Wt2b   = Wt2a + 512 * 512;                  // [256][512]
    char*   P      = ws + 10485760;                     // 102,400,000 B slot
    char*   Q      = ws + 10485760 + 102400000;         // 102,400,000 B slot
    ushort* xb     = (ushort*)P;   // [100000,256] bf16 (dead before h1 written)
    ushort* agg1b  = (ushort*)Q;   // [100000,256] bf16 (dead before h2 written)
    ushort* h1     = (ushort*)P;   // [100000,512]
    ushort* h2     = (ushort*)Q;   // [100000,512]
    ushort* agg2b  = (ushort*)P;   // [100000,512] (h1 dead)
    ushort* h3     = (ushort*)Q;   // [100000,512] (h2 dead)

    // ---- CSR build (by dst) ----
    zero_i32<<<(NN + 255) / 256, 256, 0, stream>>>(cursor, NN);
    count_deg<<<(nE + 255) / 256, 256, 0, stream>>>(dstv, cursor, nE);
    scan_excl<<<1, 1024, 0, stream>>>(cursor, off, NN);
    zero_i32<<<(NN + 255) / 256, 256, 0, stream>>>(cursor, NN);
    fill_csr<<<(nE + 255) / 256, 256, 0, stream>>>(srcv, dstv, off, cursor, csr, nE);

    // ---- weights -> bf16 transposed; x -> bf16 ----
    prep_w<<<(NFEATD * NHIDD + 255) / 256, 256, 0, stream>>>(W1a, Wt1a, NFEATD, NHIDD);
    prep_w<<<(NHIDD * NHIDD + 255) / 256, 256, 0, stream>>>(W1b, Wt1b, NHIDD, NHIDD);
    prep_w<<<(NHIDD * NHIDD + 255) / 256, 256, 0, stream>>>(W2a, Wt2a, NHIDD, NHIDD);
    prep_w<<<(NHIDD * NCLASSD + 255) / 256, 256, 0, stream>>>(W2b, Wt2b, NHIDD, NCLASSD);
    cast_f32_bf16<<<(NN * NFEATD / 8 + 255) / 256, 256, 0, stream>>>(x, xb, NN * NFEATD);

    // ---- layer 1: agg -> MLP ----
    gather256b<<<(NN * 64) / 256, 256, 0, stream>>>(xb, off, csr, eps1, agg1b);
    dim3 g1((NN + 127) / 128, NHIDD / 128);
    gemm_bt<<<g1, 256, 0, stream>>>(agg1b, Wt1a, b1a, nullptr, h1, NN, NHIDD, NFEATD, 1);
    gemm_bt<<<g1, 256, 0, stream>>>(h1, Wt1b, b1b, nullptr, h2, NN, NHIDD, NHIDD, 1);

    // ---- layer 2: agg -> MLP ----
    gather512<<<(NN * 64) / 256, 256, 0, stream>>>(h2, off, csr, eps2, agg2b);
    gemm_bt<<<g1, 256, 0, stream>>>(agg2b, Wt2a, b2a, nullptr, h3, NN, NHIDD, NHIDD, 1);
    dim3 g2((NN + 127) / 128, NCLASSD / 128);
    gemm_bt<<<g2, 256, 0, stream>>>(h3, Wt2b, b2b, (float*)d_out, nullptr, NN, NCLASSD, NHIDD, 0);
}

// Round 4
// 1025.873 us; speedup vs baseline: 1.2660x; 1.1483x over previous
//
#include <hip/hip_runtime.h>
#include <hip/hip_bf16.h>
#include <stdint.h>

#define NN 100000
#define NFEATD 256
#define NHIDD 512
#define NCLASSD 256

typedef short bf16x8 __attribute__((ext_vector_type(8)));
typedef float f32x4 __attribute__((ext_vector_type(4)));
typedef float f32x2 __attribute__((ext_vector_type(2)));

__device__ __forceinline__ float bf2f(uint32_t u) {
    union { uint32_t i; float f; } v; v.i = u << 16; return v.f;
}
__device__ __forceinline__ ushort f2bf(float f) {
    uint32_t x = __float_as_uint(f);
    uint32_t r = (x + 0x7FFF + ((x >> 16) & 1)) >> 16;
    return (ushort)r;
}

// ---------------- small utility kernels ----------------
__global__ void zero_i32(int* __restrict__ p, int n) {
    int i = blockIdx.x * 256 + threadIdx.x;
    if (i < n) p[i] = 0;
}

__global__ void count_deg(const int* __restrict__ dst, int* __restrict__ deg, int nE) {
    int e = blockIdx.x * 256 + threadIdx.x;
    if (e < nE) atomicAdd(&deg[dst[e]], 1);
}

// single-block exclusive scan over n ints, 1024 threads
__global__ __launch_bounds__(1024) void scan_excl(const int* __restrict__ deg,
                                                  int* __restrict__ off, int n) {
    __shared__ int wsum[16];
    __shared__ int carry_s;
    const int tid = threadIdx.x;
    const int lane = tid & 63, wv = tid >> 6;
    if (tid == 0) carry_s = 0;
    __syncthreads();
    for (int base = 0; base < n; base += 1024) {
        int i = base + tid;
        int v = (i < n) ? deg[i] : 0;
        int x = v;
#pragma unroll
        for (int d = 1; d < 64; d <<= 1) {
            int y = __shfl_up(x, d, 64);
            if (lane >= d) x += y;
        }
        if (lane == 63) wsum[wv] = x;
        __syncthreads();
        if (wv == 0 && lane < 16) {
            int s = wsum[lane];
#pragma unroll
            for (int d = 1; d < 16; d <<= 1) {
                int y = __shfl_up(s, d, 16);
                if (lane >= d) s += y;
            }
            wsum[lane] = s;
        }
        __syncthreads();
        int carry = carry_s;
        int wprefix = (wv == 0) ? 0 : wsum[wv - 1];
        if (i < n) off[i] = carry + wprefix + x - v;
        __syncthreads();
        if (tid == 0) carry_s = carry + wsum[15];
        __syncthreads();
    }
    if (tid == 0) off[n] = carry_s;
}

__global__ void fill_csr(const int* __restrict__ src, const int* __restrict__ dst,
                         const int* __restrict__ off, int* __restrict__ cursor,
                         int* __restrict__ csr, int nE) {
    int e = blockIdx.x * 256 + threadIdx.x;
    if (e >= nE) return;
    int d = dst[e];
    int p = off[d] + atomicAdd(&cursor[d], 1);
    csr[p] = src[e];
}

// ---------------- weight prep: [K][N] f32 -> [N][K] bf16 ----------------
__global__ void prep_w(const float* __restrict__ W, ushort* __restrict__ Wt, int K, int N) {
    int idx = blockIdx.x * 256 + threadIdx.x;
    if (idx >= K * N) return;
    int k = idx / N, n = idx - k * N;
    Wt[(size_t)n * K + k] = f2bf(W[idx]);
}

// f32 -> fp8 e4m3 cast, 8 elems/thread
__global__ void cast_f32_fp8(const float* __restrict__ a, uint8_t* __restrict__ o, int n) {
    int i = (blockIdx.x * 256 + threadIdx.x) * 8;
    if (i >= n) return;
    float4 v0 = *(const float4*)(a + i);
    float4 v1 = *(const float4*)(a + i + 4);
    int lo = __builtin_amdgcn_cvt_pk_fp8_f32(v0.x, v0.y, 0, false);
    lo = __builtin_amdgcn_cvt_pk_fp8_f32(v0.z, v0.w, lo, true);
    int hi = __builtin_amdgcn_cvt_pk_fp8_f32(v1.x, v1.y, 0, false);
    hi = __builtin_amdgcn_cvt_pk_fp8_f32(v1.z, v1.w, hi, true);
    uint2 r; r.x = (uint32_t)lo; r.y = (uint32_t)hi;
    *(uint2*)(o + i) = r;
}

// decode 4 fp8 (one uint32) -> accumulate with weight w
__device__ __forceinline__ void acc4_fp8(uint32_t p, float w, float& a0, float& a1,
                                         float& a2, float& a3) {
    f32x2 u = __builtin_amdgcn_cvt_pk_f32_fp8((int)p, false);
    f32x2 v = __builtin_amdgcn_cvt_pk_f32_fp8((int)p, true);
    a0 += w * u[0]; a1 += w * u[1]; a2 += w * v[0]; a3 += w * v[1];
}

// ---------------- CSR gather: agg[n] = (1+eps)*x[n] + sum_{s in nbr(n)} x[s] ---------
// one wave per node, F=256 fp8 input (uint/lane = 4 fp8), unroll 4, bf16 out
__global__ void gather256f8(const uint8_t* __restrict__ X8, const int* __restrict__ off,
                            const int* __restrict__ csr, const float* __restrict__ eps,
                            ushort* __restrict__ out) {
    int node = (blockIdx.x * 256 + threadIdx.x) >> 6;
    if (node >= NN) return;
    int lane = threadIdx.x & 63;
    float sc = 1.0f + *eps;
    const uint32_t* X1 = (const uint32_t*)X8;  // 64 uints per row
    float a0 = 0, a1 = 0, a2 = 0, a3 = 0;
    acc4_fp8(X1[(size_t)node * 64 + lane], sc, a0, a1, a2, a3);
    int e = off[node], e1 = off[node + 1];
    for (; e + 3 < e1; e += 4) {
        int s0 = csr[e], s1 = csr[e + 1], s2 = csr[e + 2], s3 = csr[e + 3];
        uint32_t p0 = X1[(size_t)s0 * 64 + lane];
        uint32_t p1 = X1[(size_t)s1 * 64 + lane];
        uint32_t p2 = X1[(size_t)s2 * 64 + lane];
        uint32_t p3 = X1[(size_t)s3 * 64 + lane];
        acc4_fp8(p0, 1.f, a0, a1, a2, a3);
        acc4_fp8(p1, 1.f, a0, a1, a2, a3);
        acc4_fp8(p2, 1.f, a0, a1, a2, a3);
        acc4_fp8(p3, 1.f, a0, a1, a2, a3);
    }
    for (; e < e1; ++e)
        acc4_fp8(X1[(size_t)csr[e] * 64 + lane], 1.f, a0, a1, a2, a3);
    uint2 r;
    r.x = (uint32_t)f2bf(a0) | ((uint32_t)f2bf(a1) << 16);
    r.y = (uint32_t)f2bf(a2) | ((uint32_t)f2bf(a3) << 16);
    *(uint2*)(out + (size_t)node * 256 + lane * 4) = r;
}

// one wave per node, F=512 fp8 input (uint2/lane = 8 fp8), unroll 4, bf16 out
__global__ void gather512f8(const uint8_t* __restrict__ H8, const int* __restrict__ off,
                            const int* __restrict__ csr, const float* __restrict__ eps,
                            ushort* __restrict__ out) {
    int node = (blockIdx.x * 256 + threadIdx.x) >> 6;
    if (node >= NN) return;
    int lane = threadIdx.x & 63;
    float sc = 1.0f + *eps;
    const uint2* H2 = (const uint2*)H8;  // 64 uint2 per row
    float a0 = 0, a1 = 0, a2 = 0, a3 = 0, a4 = 0, a5 = 0, a6 = 0, a7 = 0;
    {
        uint2 p = H2[(size_t)node * 64 + lane];
        acc4_fp8(p.x, sc, a0, a1, a2, a3);
        acc4_fp8(p.y, sc, a4, a5, a6, a7);
    }
    int e = off[node], e1 = off[node + 1];
    for (; e + 3 < e1; e += 4) {
        int s0 = csr[e], s1 = csr[e + 1], s2 = csr[e + 2], s3 = csr[e + 3];
        uint2 p0 = H2[(size_t)s0 * 64 + lane];
        uint2 p1 = H2[(size_t)s1 * 64 + lane];
        uint2 p2 = H2[(size_t)s2 * 64 + lane];
        uint2 p3 = H2[(size_t)s3 * 64 + lane];
        acc4_fp8(p0.x, 1.f, a0, a1, a2, a3); acc4_fp8(p0.y, 1.f, a4, a5, a6, a7);
        acc4_fp8(p1.x, 1.f, a0, a1, a2, a3); acc4_fp8(p1.y, 1.f, a4, a5, a6, a7);
        acc4_fp8(p2.x, 1.f, a0, a1, a2, a3); acc4_fp8(p2.y, 1.f, a4, a5, a6, a7);
        acc4_fp8(p3.x, 1.f, a0, a1, a2, a3); acc4_fp8(p3.y, 1.f, a4, a5, a6, a7);
    }
    for (; e < e1; ++e) {
        uint2 p0 = H2[(size_t)csr[e] * 64 + lane];
        acc4_fp8(p0.x, 1.f, a0, a1, a2, a3);
        acc4_fp8(p0.y, 1.f, a4, a5, a6, a7);
    }
    uint4 r;
    r.x = (uint32_t)f2bf(a0) | ((uint32_t)f2bf(a1) << 16);
    r.y = (uint32_t)f2bf(a2) | ((uint32_t)f2bf(a3) << 16);
    r.z = (uint32_t)f2bf(a4) | ((uint32_t)f2bf(a5) << 16);
    r.w = (uint32_t)f2bf(a6) | ((uint32_t)f2bf(a7) << 16);
    *(uint4*)(out + (size_t)node * 512 + lane * 8) = r;
}

// ---------------- GEMM: C[M,N] = A[M,K](bf16) * Bt[N,K](bf16)^T + bias, opt relu ----
// out: f32 (outf) | fp8 e4m3 (out8) | bf16 (outb)
__global__ __launch_bounds__(256) void gemm_bt(
    const ushort* __restrict__ A, const ushort* __restrict__ Bt,
    const float* __restrict__ bias, float* __restrict__ outf,
    uint8_t* __restrict__ out8, ushort* __restrict__ outb,
    int M, int N, int K, int relu)
{
    __shared__ ushort As[128 * 32];
    __shared__ ushort Bs[128 * 32];
    const int tid = threadIdx.x;
    const int wave = tid >> 6, lane = tid & 63;
    const int quad = lane >> 4, lrow = lane & 15;
    const int wr = wave >> 1, wc = wave & 1;
    const int row0 = blockIdx.x * 128, col0 = blockIdx.y * 128;

    f32x4 acc[4][4] = {};

    for (int k0 = 0; k0 < K; k0 += 32) {
#pragma unroll
        for (int it = 0; it < 2; ++it) {
            int chunk = it * 256 + tid;        // lds dst = wave-uniform base + lane*16B
            int r = chunk >> 2, c = chunk & 3;
            int gr = row0 + r; if (gr > M - 1) gr = M - 1;
            const ushort* gp = A + (size_t)gr * K + (k0 + c * 8);
            __builtin_amdgcn_global_load_lds((const __attribute__((address_space(1))) void*)gp,
                (__attribute__((address_space(3))) void*)(As + chunk * 8), 16, 0, 0);
        }
#pragma unroll
        for (int it = 0; it < 2; ++it) {
            int chunk = it * 256 + tid;
            int r = chunk >> 2, c = chunk & 3;
            const ushort* gp = Bt + (size_t)(col0 + r) * K + (k0 + c * 8);
            __builtin_amdgcn_global_load_lds((const __attribute__((address_space(1))) void*)gp,
                (__attribute__((address_space(3))) void*)(Bs + chunk * 8), 16, 0, 0);
        }
        __syncthreads();

        bf16x8 af[4], bfr[4];
#pragma unroll
        for (int i = 0; i < 4; ++i)
            af[i] = *(const bf16x8*)(As + (wr * 64 + i * 16 + lrow) * 32 + quad * 8);
#pragma unroll
        for (int j = 0; j < 4; ++j)
            bfr[j] = *(const bf16x8*)(Bs + (wc * 64 + j * 16 + lrow) * 32 + quad * 8);
#pragma unroll
        for (int i = 0; i < 4; ++i)
#pragma unroll
            for (int j = 0; j < 4; ++j)
                acc[i][j] = __builtin_amdgcn_mfma_f32_16x16x32_bf16(af[i], bfr[j], acc[i][j], 0, 0, 0);
        __syncthreads();
    }

    // epilogue: C/D layout col=lane&15, row=quad*4+reg
#pragma unroll
    for (int i = 0; i < 4; ++i) {
        int rbase = row0 + wr * 64 + i * 16 + quad * 4;
#pragma unroll
        for (int j = 0; j < 4; ++j) {
            int c = col0 + wc * 64 + j * 16 + lrow;
            float bv = bias[c];
#pragma unroll
            for (int g = 0; g < 4; ++g) {
                int rr = rbase + g;
                if (rr < M) {
                    float v = acc[i][j][g] + bv;
                    if (relu) v = fmaxf(v, 0.f);
                    if (outf) outf[(size_t)rr * N + c] = v;
                    else if (out8) {
                        int enc = __builtin_amdgcn_cvt_pk_fp8_f32(v, v, 0, false);
                        out8[(size_t)rr * N + c] = (uint8_t)(enc & 0xff);
                    }
                    else outb[(size_t)rr * N + c] = f2bf(v);
                }
            }
        }
    }
}

extern "C" void kernel_launch(void* const* d_in, const int* in_sizes, int n_in,
                              void* d_out, int out_size, void* d_ws, size_t ws_size,
                              hipStream_t stream) {
    const float* x    = (const float*)d_in[0];
    const int*   ei   = (const int*)d_in[1];
    const float* W1a  = (const float*)d_in[2];
    const float* b1a  = (const float*)d_in[3];
    const float* W1b  = (const float*)d_in[4];
    const float* b1b  = (const float*)d_in[5];
    const float* W2a  = (const float*)d_in[6];
    const float* b2a  = (const float*)d_in[7];
    const float* W2b  = (const float*)d_in[8];
    const float* b2b  = (const float*)d_in[9];
    const float* eps1 = (const float*)d_in[10];
    const float* eps2 = (const float*)d_in[11];
    const int nE = in_sizes[1] / 2;
    const int* srcv = ei;
    const int* dstv = ei + nE;

    // ---- compact workspace layout (~215 MB) ----
    char* ws = (char*)d_ws;
    int*    off    = (int*)(ws);                        // 100001 ints
    int*    cursor = (int*)(ws + 524288);               // 100000 ints
    int*    csr    = (int*)(ws + 1048576);              // 1.6M ints
    ushort* Wt1a   = (ushort*)(ws + 8388608);           // [512][256] bf16
    ushort* Wt1b   = Wt1a + 512 * 256;                  // [512][512]
    ushort* Wt2a   = Wt1b + 512 * 512;                  // [512][512]
    ushort* Wt2b   = Wt2a + 512 * 512;                  // [256][512]
    char*   P      = ws + 10485760;                     // 102,400,000 B slot
    char*   Q      = ws + 10485760 + 102400000;         // 102,400,000 B slot
    uint8_t* x8    = (uint8_t*)P;  // [100000,256] fp8 (dead before h1 written)
    ushort* agg1b  = (ushort*)Q;   // [100000,256] bf16 (dead before h2f8 written)
    ushort* h1     = (ushort*)P;   // [100000,512] bf16
    uint8_t* h2f8  = (uint8_t*)Q;  // [100000,512] fp8
    ushort* agg2b  = (ushort*)P;   // [100000,512] bf16 (h1 dead)
    ushort* h3     = (ushort*)Q;   // [100000,512] bf16 (h2f8 dead)

    // ---- CSR build (by dst) ----
    zero_i32<<<(NN + 255) / 256, 256, 0, stream>>>(cursor, NN);
    count_deg<<<(nE + 255) / 256, 256, 0, stream>>>(dstv, cursor, nE);
    scan_excl<<<1, 1024, 0, stream>>>(cursor, off, NN);
    zero_i32<<<(NN + 255) / 256, 256, 0, stream>>>(cursor, NN);
    fill_csr<<<(nE + 255) / 256, 256, 0, stream>>>(srcv, dstv, off, cursor, csr, nE);

    // ---- weights -> bf16 transposed; x -> fp8 ----
    prep_w<<<(NFEATD * NHIDD + 255) / 256, 256, 0, stream>>>(W1a, Wt1a, NFEATD, NHIDD);
    prep_w<<<(NHIDD * NHIDD + 255) / 256, 256, 0, stream>>>(W1b, Wt1b, NHIDD, NHIDD);
    prep_w<<<(NHIDD * NHIDD + 255) / 256, 256, 0, stream>>>(W2a, Wt2a, NHIDD, NHIDD);
    prep_w<<<(NHIDD * NCLASSD + 255) / 256, 256, 0, stream>>>(W2b, Wt2b, NHIDD, NCLASSD);
    cast_f32_fp8<<<(NN * NFEATD / 8 + 255) / 256, 256, 0, stream>>>(x, x8, NN * NFEATD);

    // ---- layer 1: agg -> MLP ----
    gather256f8<<<(NN * 64) / 256, 256, 0, stream>>>(x8, off, csr, eps1, agg1b);
    dim3 g1((NN + 127) / 128, NHIDD / 128);
    gemm_bt<<<g1, 256, 0, stream>>>(agg1b, Wt1a, b1a, nullptr, nullptr, h1, NN, NHIDD, NFEATD, 1);
    gemm_bt<<<g1, 256, 0, stream>>>(h1, Wt1b, b1b, nullptr, h2f8, nullptr, NN, NHIDD, NHIDD, 1);

    // ---- layer 2: agg -> MLP ----
    gather512f8<<<(NN * 64) / 256, 256, 0, stream>>>(h2f8, off, csr, eps2, agg2b);
    gemm_bt<<<g1, 256, 0, stream>>>(agg2b, Wt2a, b2a, nullptr, nullptr, h3, NN, NHIDD, NHIDD, 1);
    dim3 g2((NN + 127) / 128, NCLASSD / 128);
    gemm_bt<<<g2, 256, 0, stream>>>(h3, Wt2b, b2b, (float*)d_out, nullptr, nullptr, NN, NCLASSD, NHIDD, 0);
}